// Round 7
// baseline (210.067 us; speedup 1.0000x reference)
//
#include <hip/hip_runtime.h>
#include <math.h>

typedef _Float16 f16;
typedef _Float16 f16x4 __attribute__((ext_vector_type(4)));
typedef _Float16 f16x8 __attribute__((ext_vector_type(8)));
typedef float    f32x4 __attribute__((ext_vector_type(4)));

typedef const __attribute__((address_space(1))) void gv_t;   // global
typedef __attribute__((address_space(3))) void lv_t;         // LDS

#define NSEQ 1024
#define CD   128
#define LT   136   // pre-kernel LDS f16 row stride (272 B = 17*16 B, keeps b128 alignment)

// khs: [bh][g16 0..63][cs 0..3][lane 0..63][j 0..7]   (131072 f16 per bh)
//   value = Ktr[key = (g16>>1)*32 + 8*(lq>>2) + 4*(g16&1) + (lq&3)][c = cs*32+quad*8+j]
// vhs: [bh][k32 0..31][cb 0..7][lane 0..63][j 0..7]
//   value = Vtr[key = k32*32 + quad*8 + j][c = cb*16 + lq]
// Both are exact MFMA fragment order AND exact linear order for global_load_lds staging.
// With 32-key attn tiles (one g16 PAIR + one k32), the QK^T score slot (quad*4+r) of
// group g holds key_local = quad*8 + g*4 + r, so pf[j=g*4+r] = p[g*4+r] feeds PV's
// B-operand (key = quad*8 + j) with NO permutation.

__global__ __launch_bounds__(256)
void ipa_pre(const float* __restrict__ kg, const float* __restrict__ vg,
             const float* __restrict__ Lm, f16* __restrict__ khs, f16* __restrict__ vhs)
{
    __shared__ float LL[64 * 16];
    __shared__ __align__(16) f16 Kt[64 * LT];
    __shared__ __align__(16) f16 Vt[64 * LT];
    const int bx = blockIdx.x, nt = blockIdx.y, tid = threadIdx.x;
    const int bh = ((bx & 7) << 3) | (bx >> 3);   // XCD x <-> bh 8x..8x+7 (matches attn)
    const int b  = bh >> 3;
    const float* Lb = Lm + ((size_t)b * NSEQ + nt * 64) * 16;
    for (int t = tid; t < 64 * 16; t += 256) LL[t] = Lb[t];
    __syncthreads();

    const size_t base = ((size_t)bh * NSEQ + nt * 64) * CD;
    #pragma unroll
    for (int it = 0; it < 8; ++it) {
        int g = it * 256 + tid;
        int row = g >> 5, cg = g & 31;
        size_t idx = base + row * CD + cg * 4;
        const float* Lr = &LL[row * 16];
        float4 xk = *(const float4*)(kg + idx);
        float4 xv = *(const float4*)(vg + idx);
        float4 yk = xk, yv = xv;
        if (cg >= 2) {
            float t0 = xk.x, t1 = -xk.y, t2 = -xk.z, t3 = -xk.w;   // K: M = L^T eta
            yk.x = Lr[0]*t0 + Lr[4]*t1 + Lr[8] *t2 + Lr[12]*t3;
            yk.y = Lr[1]*t0 + Lr[5]*t1 + Lr[9] *t2 + Lr[13]*t3;
            yk.z = Lr[2]*t0 + Lr[6]*t1 + Lr[10]*t2 + Lr[14]*t3;
            yk.w = Lr[3]*t0 + Lr[7]*t1 + Lr[11]*t2 + Lr[15]*t3;
            t0 = xv.x; t1 = -xv.y; t2 = -xv.z; t3 = -xv.w;         // V: M = eta L^T eta
            yv.x =  (Lr[0]*t0 + Lr[4]*t1 + Lr[8] *t2 + Lr[12]*t3);
            yv.y = -(Lr[1]*t0 + Lr[5]*t1 + Lr[9] *t2 + Lr[13]*t3);
            yv.z = -(Lr[2]*t0 + Lr[6]*t1 + Lr[10]*t2 + Lr[14]*t3);
            yv.w = -(Lr[3]*t0 + Lr[7]*t1 + Lr[11]*t2 + Lr[15]*t3);
        }
        f16x4 hk = {(f16)yk.x, (f16)yk.y, (f16)yk.z, (f16)yk.w};
        f16x4 hv = {(f16)yv.x, (f16)yv.y, (f16)yv.z, (f16)yv.w};
        *(f16x4*)&Kt[row * LT + cg * 4] = hk;
        *(f16x4*)&Vt[row * LT + cg * 4] = hv;
    }
    __syncthreads();

    // staged K out (b128 LDS read -> fully coalesced global store)
    f16* kout = khs + (size_t)bh * 131072 + (size_t)nt * 4 * 4 * 512;
    #pragma unroll
    for (int it = 0; it < 4; ++it) {
        int slot = it * 256 + tid;                 // (g16l, cs, L)
        int g16l = slot >> 8, cs = (slot >> 6) & 3, L = slot & 63;
        int lq = L & 15, quad = L >> 4;
        int keyl = ((g16l >> 1) << 5) + ((lq >> 2) << 3) + ((g16l & 1) << 2) + (lq & 3);
        f16x8 kv = *(const f16x8*)&Kt[keyl * LT + cs * 32 + quad * 8];
        *(f16x8*)(kout + (g16l * 4 + cs) * 512 + L * 8) = kv;
    }
    // staged V^T out (scalar LDS column reads -> coalesced global store)
    f16* vout = vhs + (size_t)bh * 131072 + (size_t)nt * 2 * 8 * 512;
    #pragma unroll
    for (int it = 0; it < 4; ++it) {
        int slot = it * 256 + tid;                 // (k32l, cb, L)
        int k32l = slot >> 9, cb = (slot >> 6) & 7, L = slot & 63;
        int lq = L & 15, quad = L >> 4;
        int c = cb * 16 + lq;
        f16x8 o;
        #pragma unroll
        for (int j = 0; j < 8; ++j)
            o[j] = Vt[(k32l * 32 + quad * 8 + j) * LT + c];
        *(f16x8*)(vout + (k32l * 8 + cb) * 512 + L * 8) = o;
    }
}

// ------- attention: counted-vmcnt 3-buffer pipeline (T3+T4), no barrier drains -------
// R6 finding: occupancy 19->34% with identical 79.6us => not occupancy/memory-path bound.
// Invariant cost 0.73 cy/(q,key)/CU with all pipes <50% = the 2-phase barrier-drain stall
// (m233): __syncthreads() drains vmcnt(0) every tile, exposing staging latency 32x.
// Fix: 3 LDS buffers; per iter: s_waitcnt vmcnt(4) (tile t landed; t+1,t+2 stay in
// flight ACROSS the barrier) -> raw s_barrier (no drain; also fences buffer reuse) ->
// re-stage freed buffer for t+2 -> compute t. Exactly 4 gl_lds per wave per tile; no
// other VMEM loads in the loop, so the count is deterministic.
__global__ __launch_bounds__(256, 2)
void ipa_attn(const float* __restrict__ qg, const f16* __restrict__ khs,
              const f16* __restrict__ vhs, const float* __restrict__ Lm,
              float* __restrict__ out)
{
    __shared__ __align__(16) f16 sK[3][4096];   // 8 KB per buffer (32 keys x 128 c)
    __shared__ __align__(16) f16 sV[3][4096];
    const int n = blockIdx.x;                   // 1024 blocks = 64 bh x 16 qblk
    const int bh = ((n & 7) << 3) | ((n >> 3) & 7);   // XCD-local bh octet (matches pre)
    const int b  = bh >> 3;
    const int tid = threadIdx.x;
    const int w = tid >> 6, lane = tid & 63, lq = lane & 15, quad = lane >> 4;
    const int qblk = n >> 6;                    // 0..15
    const int q0 = qblk * 64 + w * 16;          // wave owns 16 q-rows
    const f16* kbh = khs + (size_t)bh * 131072;
    const f16* vbh = vhs + (size_t)bh * 131072;
    const float sc2 = 0.12751744154226873f;     // (1/sqrt(128)) * log2(e)

    // stage one 32-key tile (8 KB K + 8 KB V) into buffer nb: 4 gl_lds per wave
    auto stage = [&](int nb, int it) {
        const char* kp = (const char*)(kbh + (size_t)it * 4096);
        const char* vp = (const char*)(vbh + (size_t)it * 4096);
        char* kd = (char*)&sK[nb][0];
        char* vd = (char*)&sV[nb][0];
        #pragma unroll
        for (int j = 0; j < 2; ++j) {
            int off = (w * 2 + j) * 1024;       // wave-uniform LDS dest; per-lane global src
            __builtin_amdgcn_global_load_lds((gv_t*)(kp + off + lane * 16),
                                             (lv_t*)(kd + off), 16, 0, 0);
            __builtin_amdgcn_global_load_lds((gv_t*)(vp + off + lane * 16),
                                             (lv_t*)(vd + off), 16, 0, 0);
        }
    };

    // ---- Q: load fp32, transform (M = eta L^T eta), scale, frags (16 rows) ----
    f16x8 qf[4];
    {
        int qrow = q0 + lq;
        const float* Lr = Lm + ((size_t)b * NSEQ + qrow) * 16;
        const float* qp = qg + ((size_t)bh * NSEQ + qrow) * CD;
        float Lv[16];
        #pragma unroll
        for (int i = 0; i < 4; ++i) *(float4*)&Lv[i*4] = *(const float4*)(Lr + i*4);
        #pragma unroll
        for (int cs = 0; cs < 4; ++cs) {
            int c0 = cs * 32 + quad * 8;
            float4 x0 = *(const float4*)(qp + c0);
            float4 x1 = *(const float4*)(qp + c0 + 4);
            if (c0 >= 8) {
                float t0 = x0.x, t1 = -x0.y, t2 = -x0.z, t3 = -x0.w;
                float4 y;
                y.x =  (Lv[0]*t0 + Lv[4]*t1 + Lv[8] *t2 + Lv[12]*t3);
                y.y = -(Lv[1]*t0 + Lv[5]*t1 + Lv[9] *t2 + Lv[13]*t3);
                y.z = -(Lv[2]*t0 + Lv[6]*t1 + Lv[10]*t2 + Lv[14]*t3);
                y.w = -(Lv[3]*t0 + Lv[7]*t1 + Lv[11]*t2 + Lv[15]*t3);
                x0 = y;
                t0 = x1.x; t1 = -x1.y; t2 = -x1.z; t3 = -x1.w;
                y.x =  (Lv[0]*t0 + Lv[4]*t1 + Lv[8] *t2 + Lv[12]*t3);
                y.y = -(Lv[1]*t0 + Lv[5]*t1 + Lv[9] *t2 + Lv[13]*t3);
                y.z = -(Lv[2]*t0 + Lv[6]*t1 + Lv[10]*t2 + Lv[14]*t3);
                y.w = -(Lv[3]*t0 + Lv[7]*t1 + Lv[11]*t2 + Lv[15]*t3);
                x1 = y;
            }
            qf[cs] = (f16x8){(f16)(x0.x*sc2), (f16)(x0.y*sc2), (f16)(x0.z*sc2), (f16)(x0.w*sc2),
                             (f16)(x1.x*sc2), (f16)(x1.y*sc2), (f16)(x1.z*sc2), (f16)(x1.w*sc2)};
        }
    }

    f32x4 oacc[8];
    #pragma unroll
    for (int cb = 0; cb < 8; ++cb) oacc[cb] = (f32x4){0.f, 0.f, 0.f, 0.f};
    float mrun = -1e30f, lrun = 0.f;

    stage(0, 0);
    stage(1, 1);

    int cur = 0;                                    // rotating buffer index = it % 3
    for (int it = 0; it < 32; ++it) {
        // tile it's 4 loads retired; tiles it+1, it+2 remain in flight across the barrier
        if (it < 31) asm volatile("s_waitcnt vmcnt(4)" ::: "memory");
        else         asm volatile("s_waitcnt vmcnt(0)" ::: "memory");
        __builtin_amdgcn_s_barrier();               // raw barrier: no compiler vmcnt(0) drain
        if (it < 30) {
            int nb = cur - 1; if (nb < 0) nb += 3;  // buffer freed by the barrier above
            stage(nb, it + 2);
        }

        const f16* kb = &sK[cur][0];
        const f16* vb = &sV[cur][0];

        // QK^T: 8 MFMA, kf live-range = one iteration of this loop (8 regs)
        f32x4 s[2];
        s[0] = (f32x4){0.f, 0.f, 0.f, 0.f};
        s[1] = (f32x4){0.f, 0.f, 0.f, 0.f};
        #pragma unroll
        for (int cs = 0; cs < 4; ++cs) {
            f16x8 kf0 = *(const f16x8*)&kb[(cs    ) * 512 + lane * 8];
            f16x8 kf1 = *(const f16x8*)&kb[(cs + 4) * 512 + lane * 8];
            s[0] = __builtin_amdgcn_mfma_f32_16x16x32_f16(kf0, qf[cs], s[0], 0, 0, 0);
            s[1] = __builtin_amdgcn_mfma_f32_16x16x32_f16(kf1, qf[cs], s[1], 0, 0, 0);
        }

        // exp2-domain online softmax over 32 keys; l kept per-lane (quad-reduced at end)
        float mx = fmaxf(fmaxf(fmaxf(s[0].x, s[0].y), fmaxf(s[0].z, s[0].w)),
                         fmaxf(fmaxf(s[1].x, s[1].y), fmaxf(s[1].z, s[1].w)));
        mx = fmaxf(mx, __shfl_xor(mx, 16, 64));
        mx = fmaxf(mx, __shfl_xor(mx, 32, 64));
        float mnew = fmaxf(mrun, mx);
        // defer-rescale (bit-exact): when no lane sees a new max, alpha==1 exactly
        if (!__all(mx <= mrun)) {
            float alpha = exp2f(mrun - mnew);
            lrun *= alpha;
            #pragma unroll
            for (int cb = 0; cb < 8; ++cb) oacc[cb] *= alpha;
            mrun = mnew;
        }
        float p[8];
        p[0] = exp2f(s[0].x - mnew); p[1] = exp2f(s[0].y - mnew);
        p[2] = exp2f(s[0].z - mnew); p[3] = exp2f(s[0].w - mnew);
        p[4] = exp2f(s[1].x - mnew); p[5] = exp2f(s[1].y - mnew);
        p[6] = exp2f(s[1].z - mnew); p[7] = exp2f(s[1].w - mnew);
        lrun += ((p[0]+p[1]) + (p[2]+p[3])) + ((p[4]+p[5]) + (p[6]+p[7]));
        f16x8 pf = {(f16)p[0],(f16)p[1],(f16)p[2],(f16)p[3],
                    (f16)p[4],(f16)p[5],(f16)p[6],(f16)p[7]};

        // PV: 8 MFMA, vf live-range = one loop iteration (4 regs)
        #pragma unroll
        for (int cb = 0; cb < 8; ++cb) {
            f16x8 vf = *(const f16x8*)&vb[cb * 512 + lane * 8];
            oacc[cb] = __builtin_amdgcn_mfma_f32_16x16x32_f16(vf, pf, oacc[cb], 0, 0, 0);
        }

        if (++cur == 3) cur = 0;
    }

    // ---- epilogue: quad-reduce l, normalize, final frame transform (M = L), store ----
    {
        float l = lrun;
        l += __shfl_xor(l, 16, 64);
        l += __shfl_xor(l, 32, 64);
        float invl = 1.0f / l;
        int qrow = q0 + lq;
        const float* Lr = Lm + ((size_t)b * NSEQ + qrow) * 16;
        float* ob = out + ((size_t)bh * NSEQ + qrow) * CD;
        #pragma unroll
        for (int cb = 0; cb < 8; ++cb) {
            int c0 = cb * 16 + quad * 4;
            float o0 = oacc[cb].x*invl, o1 = oacc[cb].y*invl;
            float o2 = oacc[cb].z*invl, o3 = oacc[cb].w*invl;
            float4 r;
            if (c0 >= 8) {
                r.x = Lr[0] *o0 + Lr[1] *o1 + Lr[2] *o2 + Lr[3] *o3;
                r.y = Lr[4] *o0 + Lr[5] *o1 + Lr[6] *o2 + Lr[7] *o3;
                r.z = Lr[8] *o0 + Lr[9] *o1 + Lr[10]*o2 + Lr[11]*o3;
                r.w = Lr[12]*o0 + Lr[13]*o1 + Lr[14]*o2 + Lr[15]*o3;
            } else {
                r.x = o0; r.y = o1; r.z = o2; r.w = o3;
            }
            *(float4*)(ob + c0) = r;
        }
    }
}

extern "C" void kernel_launch(void* const* d_in, const int* in_sizes, int n_in,
                              void* d_out, int out_size, void* d_ws, size_t ws_size,
                              hipStream_t stream) {
    const float* q = (const float*)d_in[0];
    const float* k = (const float*)d_in[1];
    const float* v = (const float*)d_in[2];
    const float* L = (const float*)d_in[3];
    float* o = (float*)d_out;
    f16* khs = (f16*)d_ws;                       // 16.78 MB
    f16* vhs = khs + (size_t)64 * 131072;        // 16.78 MB
    dim3 grid1(64, 16);
    ipa_pre<<<grid1, 256, 0, stream>>>(k, v, L, khs, vhs);
    ipa_attn<<<1024, 256, 0, stream>>>(q, khs, vhs, L, o);
}

// Round 8
// 197.650 us; speedup vs baseline: 1.0628x; 1.0628x over previous
//
#include <hip/hip_runtime.h>
#include <math.h>

typedef _Float16 f16;
typedef _Float16 f16x2 __attribute__((ext_vector_type(2)));
typedef _Float16 f16x4 __attribute__((ext_vector_type(4)));
typedef _Float16 f16x8 __attribute__((ext_vector_type(8)));
typedef float    f32x4 __attribute__((ext_vector_type(4)));
typedef float    f32x16 __attribute__((ext_vector_type(16)));

typedef const __attribute__((address_space(1))) void gv_t;   // global
typedef __attribute__((address_space(3))) void lv_t;         // LDS

#define NSEQ 1024
#define CD   128
#define LT   136   // pre-kernel LDS f16 row stride (272 B = 17*16 B, keeps b128 alignment)

// ---- 32x32x16 fragment-linear workspace layouts (8 KB per 32-key tile) ----
// khs: [bh][kt 0..31][cs16 0..7][lane 0..63][j 0..7]
//   value = Ktr[key = kt*32 + (lane&31)][c = cs16*16 + 8*(lane>>5) + j]
//   = exact A-operand fragment of mfma_32x32x16 (row = lane&31, k = 8*(lane>>5)+j).
// vhs: [bh][kt 0..31][cb 0..3][kh 0..1][lane 0..63][j 0..7]
//   value = Vtr[c = cb*32 + (lane&31)][key = kt*32 + kh*16 + 8*(lane>>5) + j]
//   = exact A-operand fragment for PV (rows = c, k = key16 of half kh).
// Both are linear in (lane,j) -> global_load_lds staging works unchanged.

__global__ __launch_bounds__(256)
void ipa_pre(const float* __restrict__ kg, const float* __restrict__ vg,
             const float* __restrict__ Lm, f16* __restrict__ khs, f16* __restrict__ vhs)
{
    __shared__ float LL[64 * 16];
    __shared__ __align__(16) f16 Kt[64 * LT];
    __shared__ __align__(16) f16 Vt[64 * LT];
    const int bx = blockIdx.x, nt = blockIdx.y, tid = threadIdx.x;
    const int bh = ((bx & 7) << 3) | (bx >> 3);   // XCD x <-> bh 8x..8x+7 (matches attn)
    const int b  = bh >> 3;
    const float* Lb = Lm + ((size_t)b * NSEQ + nt * 64) * 16;
    for (int t = tid; t < 64 * 16; t += 256) LL[t] = Lb[t];
    __syncthreads();

    const size_t base = ((size_t)bh * NSEQ + nt * 64) * CD;
    #pragma unroll
    for (int it = 0; it < 8; ++it) {
        int g = it * 256 + tid;
        int row = g >> 5, cg = g & 31;
        size_t idx = base + row * CD + cg * 4;
        const float* Lr = &LL[row * 16];
        float4 xk = *(const float4*)(kg + idx);
        float4 xv = *(const float4*)(vg + idx);
        float4 yk = xk, yv = xv;
        if (cg >= 2) {
            float t0 = xk.x, t1 = -xk.y, t2 = -xk.z, t3 = -xk.w;   // K: M = L^T eta
            yk.x = Lr[0]*t0 + Lr[4]*t1 + Lr[8] *t2 + Lr[12]*t3;
            yk.y = Lr[1]*t0 + Lr[5]*t1 + Lr[9] *t2 + Lr[13]*t3;
            yk.z = Lr[2]*t0 + Lr[6]*t1 + Lr[10]*t2 + Lr[14]*t3;
            yk.w = Lr[3]*t0 + Lr[7]*t1 + Lr[11]*t2 + Lr[15]*t3;
            t0 = xv.x; t1 = -xv.y; t2 = -xv.z; t3 = -xv.w;         // V: M = eta L^T eta
            yv.x =  (Lr[0]*t0 + Lr[4]*t1 + Lr[8] *t2 + Lr[12]*t3);
            yv.y = -(Lr[1]*t0 + Lr[5]*t1 + Lr[9] *t2 + Lr[13]*t3);
            yv.z = -(Lr[2]*t0 + Lr[6]*t1 + Lr[10]*t2 + Lr[14]*t3);
            yv.w = -(Lr[3]*t0 + Lr[7]*t1 + Lr[11]*t2 + Lr[15]*t3);
        }
        f16x4 hk = {(f16)yk.x, (f16)yk.y, (f16)yk.z, (f16)yk.w};
        f16x4 hv = {(f16)yv.x, (f16)yv.y, (f16)yv.z, (f16)yv.w};
        *(f16x4*)&Kt[row * LT + cg * 4] = hk;
        *(f16x4*)&Vt[row * LT + cg * 4] = hv;
    }
    __syncthreads();

    // K out: [kt2][cs16][L][j] <- Kt[kt2*32 + (L&31)][cs16*16 + 8*(L>>5) + j]  (b128 reads)
    f16* kout = khs + (size_t)bh * 131072 + (size_t)(nt * 2) * 4096;
    #pragma unroll
    for (int it = 0; it < 4; ++it) {
        int slot = it * 256 + tid;
        int kt2 = slot >> 9, cs16 = (slot >> 6) & 7, L = slot & 63;
        int lq5 = L & 31, h = L >> 5;
        f16x8 kv = *(const f16x8*)&Kt[(kt2 * 32 + lq5) * LT + cs16 * 16 + 8 * h];
        *(f16x8*)(kout + (size_t)kt2 * 4096 + cs16 * 512 + L * 8) = kv;
    }
    // V out: [kt2][cb][kh][L][j] <- Vt[kt2*32 + kh*16 + 8*(L>>5) + j][cb*32 + (L&31)]
    f16* vout = vhs + (size_t)bh * 131072 + (size_t)(nt * 2) * 4096;
    #pragma unroll
    for (int it = 0; it < 4; ++it) {
        int slot = it * 256 + tid;
        int kt2 = slot >> 9, cb = (slot >> 7) & 3, kh = (slot >> 6) & 1, L = slot & 63;
        int lq5 = L & 31, h = L >> 5;
        int c = cb * 32 + lq5;
        f16x8 o;
        #pragma unroll
        for (int j = 0; j < 8; ++j)
            o[j] = Vt[(kt2 * 32 + kh * 16 + 8 * h + j) * LT + c];
        *(f16x8*)(vout + (size_t)kt2 * 4096 + (cb * 2 + kh) * 512 + L * 8) = o;
    }
}

static __device__ __forceinline__ unsigned pk2(f16 a, f16 b) {
    union { f16x2 h; unsigned u; } x; x.h = (f16x2){a, b}; return x.u;
}

// ------------- attention: 32x32x16 swapped-QK^T, in-lane softmax -------------
// Wave = 32 q-rows. QK^T = mfma(K_frag, Q_frag) -> C[key][q]: lane l holds
// P[key=(r&3)+8*(r>>2)+4*hh][q=l&31] in 16 regs (hh=l>>5). Softmax over 32 keys =
// in-lane tree over 16 + ONE shfl_xor(32). PV B-frag PA_kh[j] = P[key 16kh+8hh+j]:
// derivation gives PA from regs {8kh+0..3}/{8kh+4..7} of the two halves -> 4 u32
// shfl_xor(32) per tile (T12 pattern). Halves per-pair LDS + cuts softmax VALU.
__global__ __launch_bounds__(256, 2)
void ipa_attn(const float* __restrict__ qg, const f16* __restrict__ khs,
              const f16* __restrict__ vhs, const float* __restrict__ Lm,
              float* __restrict__ out)
{
    __shared__ __align__(16) f16 sK[2][4096];   // 8 KB per buffer (32 keys x 128 c)
    __shared__ __align__(16) f16 sV[2][4096];
    const int n = blockIdx.x;                   // 512 blocks = 64 bh x 8 qblk
    const int bh = ((n & 7) << 3) | ((n >> 3) & 7);   // XCD-local bh octet (matches pre)
    const int b  = bh >> 3;
    const int tid = threadIdx.x;
    const int w = tid >> 6, lane = tid & 63;
    const int lq5 = lane & 31, hh = lane >> 5;
    const int qblk = n >> 6;                    // 0..7
    const int q0 = qblk * 128 + w * 32;         // wave owns 32 q-rows
    const f16* kbh = khs + (size_t)bh * 131072;
    const f16* vbh = vhs + (size_t)bh * 131072;
    const float sc2 = 0.12751744154226873f;     // (1/sqrt(128)) * log2(e)

    // stage one 32-key tile (8 KB K + 8 KB V) into buffer nb: 4 gl_lds per wave
    auto stage = [&](int nb, int it) {
        const char* kp = (const char*)(kbh + (size_t)it * 4096);
        const char* vp = (const char*)(vbh + (size_t)it * 4096);
        char* kd = (char*)&sK[nb][0];
        char* vd = (char*)&sV[nb][0];
        #pragma unroll
        for (int j = 0; j < 2; ++j) {
            int off = (w * 2 + j) * 1024;       // wave-uniform LDS dest; per-lane global src
            __builtin_amdgcn_global_load_lds((gv_t*)(kp + off + lane * 16),
                                             (lv_t*)(kd + off), 16, 0, 0);
            __builtin_amdgcn_global_load_lds((gv_t*)(vp + off + lane * 16),
                                             (lv_t*)(vd + off), 16, 0, 0);
        }
    };

    // ---- Q: load fp32, transform (M = eta L^T eta), scale, B-frags ----
    // qf[cs16]: lane l holds Q[q0 + (l&31)][c = cs16*16 + 8*hh + j]  (B: row=l&31, k=8*hh+j)
    f16x8 qf[8];
    {
        int qrow = q0 + lq5;
        const float* Lr = Lm + ((size_t)b * NSEQ + qrow) * 16;
        const float* qp = qg + ((size_t)bh * NSEQ + qrow) * CD;
        float Lv[16];
        #pragma unroll
        for (int i = 0; i < 4; ++i) *(float4*)&Lv[i*4] = *(const float4*)(Lr + i*4);
        #pragma unroll
        for (int cs = 0; cs < 8; ++cs) {
            int c0 = cs * 16 + 8 * hh;
            float4 x0 = *(const float4*)(qp + c0);
            float4 x1 = *(const float4*)(qp + c0 + 4);
            if (c0 >= 8) {
                float t0 = x0.x, t1 = -x0.y, t2 = -x0.z, t3 = -x0.w;
                float4 y;
                y.x =  (Lv[0]*t0 + Lv[4]*t1 + Lv[8] *t2 + Lv[12]*t3);
                y.y = -(Lv[1]*t0 + Lv[5]*t1 + Lv[9] *t2 + Lv[13]*t3);
                y.z = -(Lv[2]*t0 + Lv[6]*t1 + Lv[10]*t2 + Lv[14]*t3);
                y.w = -(Lv[3]*t0 + Lv[7]*t1 + Lv[11]*t2 + Lv[15]*t3);
                x0 = y;
                t0 = x1.x; t1 = -x1.y; t2 = -x1.z; t3 = -x1.w;
                y.x =  (Lv[0]*t0 + Lv[4]*t1 + Lv[8] *t2 + Lv[12]*t3);
                y.y = -(Lv[1]*t0 + Lv[5]*t1 + Lv[9] *t2 + Lv[13]*t3);
                y.z = -(Lv[2]*t0 + Lv[6]*t1 + Lv[10]*t2 + Lv[14]*t3);
                y.w = -(Lv[3]*t0 + Lv[7]*t1 + Lv[11]*t2 + Lv[15]*t3);
                x1 = y;
            }
            qf[cs] = (f16x8){(f16)(x0.x*sc2), (f16)(x0.y*sc2), (f16)(x0.z*sc2), (f16)(x0.w*sc2),
                             (f16)(x1.x*sc2), (f16)(x1.y*sc2), (f16)(x1.z*sc2), (f16)(x1.w*sc2)};
        }
    }

    // O accumulators: C[c][q] tiles, cb = c/32: lane l reg r = O[c=32cb+(r&3)+8*(r>>2)+4hh][q=l&31]
    f32x16 oacc[4];
    #pragma unroll
    for (int cb = 0; cb < 4; ++cb)
        #pragma unroll
        for (int r = 0; r < 16; ++r) oacc[cb][r] = 0.f;
    float mrun = -1e30f, lrun = 0.f;

    stage(0, 0);

    for (int it = 0; it < 32; ++it) {               // 32 keys per iteration
        const int cur = it & 1;
        __syncthreads();                            // stage(cur) landed; prev-buf reads done
        if (it < 31) stage(cur ^ 1, it + 1);        // in flight under this tile's compute

        const f16* kb = &sK[cur][0];
        const f16* vb = &sV[cur][0];

        // QK^T: 8 chained MFMA over c; kf live-range = one unrolled step
        f32x16 s;
        #pragma unroll
        for (int r = 0; r < 16; ++r) s[r] = 0.f;
        #pragma unroll
        for (int cs = 0; cs < 8; ++cs) {
            f16x8 kf = *(const f16x8*)&kb[cs * 512 + lane * 8];
            s = __builtin_amdgcn_mfma_f32_32x32x16_f16(kf, qf[cs], s, 0, 0, 0);
        }

        // in-lane softmax: own 16 keys + partner half via ONE shfl
        float mx = fmaxf(s[0], s[1]);
        #pragma unroll
        for (int r = 2; r < 16; ++r) mx = fmaxf(mx, s[r]);
        mx = fmaxf(mx, __shfl_xor(mx, 32, 64));
        float mnew = fmaxf(mrun, mx);
        // defer-rescale (bit-exact): when no lane sees a new max, alpha==1 exactly
        if (!__all(mx <= mrun)) {
            float alpha = exp2f(mrun - mnew);
            lrun *= alpha;
            #pragma unroll
            for (int cb = 0; cb < 4; ++cb) oacc[cb] *= alpha;
            mrun = mnew;
        }
        float pr[16];
        f16 ph[16];
        #pragma unroll
        for (int r = 0; r < 16; ++r) { pr[r] = exp2f(s[r] - mnew); ph[r] = (f16)pr[r]; }
        float rs = ((pr[0]+pr[1])+(pr[2]+pr[3])) + ((pr[4]+pr[5])+(pr[6]+pr[7]))
                 + ((pr[8]+pr[9])+(pr[10]+pr[11])) + ((pr[12]+pr[13])+(pr[14]+pr[15]));
        lrun += rs;                                 // own-half keys; partner added at epilogue

        // PA fragments: PA_kh[j] = P[key=16kh+8hh+j]; j=0..3 from half0, 4..7 from half1,
        // both at regs (j&3)+8kh+4*hh_requester -> word-select + 2 shfl_xor(32) per kh
        f16x8 pf[2];
        #pragma unroll
        for (int kh = 0; kh < 2; ++kh) {
            unsigned wA0 = pk2(ph[8*kh+0], ph[8*kh+1]);
            unsigned wA1 = pk2(ph[8*kh+2], ph[8*kh+3]);
            unsigned wB0 = pk2(ph[8*kh+4], ph[8*kh+5]);
            unsigned wB1 = pk2(ph[8*kh+6], ph[8*kh+7]);
            unsigned send0 = hh ? wA0 : wB0;
            unsigned send1 = hh ? wA1 : wB1;
            unsigned recv0 = __shfl_xor(send0, 32, 64);
            unsigned recv1 = __shfl_xor(send1, 32, 64);
            union { unsigned u[4]; f16x8 h; } pw;
            pw.u[0] = hh ? recv0 : wA0;             // PA[0..1]
            pw.u[1] = hh ? recv1 : wA1;             // PA[2..3]
            pw.u[2] = hh ? wB0 : recv0;             // PA[4..5]
            pw.u[3] = hh ? wB1 : recv1;             // PA[6..7]
            pf[kh] = pw.h;
        }

        // PV: 8 MFMA (4 independent chains); vf live-range = one unrolled step
        #pragma unroll
        for (int cb = 0; cb < 4; ++cb)
            #pragma unroll
            for (int kh = 0; kh < 2; ++kh) {
                f16x8 vf = *(const f16x8*)&vb[(cb * 2 + kh) * 512 + lane * 8];
                oacc[cb] = __builtin_amdgcn_mfma_f32_32x32x16_f16(vf, pf[kh], oacc[cb], 0, 0, 0);
            }
    }

    // ---- epilogue: combine halves' l, normalize, final transform (M = L), store ----
    {
        float l = lrun + __shfl_xor(lrun, 32, 64);
        float invl = 1.0f / l;
        int qrow = q0 + lq5;
        const float* Lr = Lm + ((size_t)b * NSEQ + qrow) * 16;
        float Lv[16];
        #pragma unroll
        for (int i = 0; i < 4; ++i) *(float4*)&Lv[i*4] = *(const float4*)(Lr + i*4);
        float* ob = out + ((size_t)bh * NSEQ + qrow) * CD;
        #pragma unroll
        for (int cb = 0; cb < 4; ++cb) {
            #pragma unroll
            for (int rg = 0; rg < 4; ++rg) {
                int c0 = cb * 32 + rg * 8 + 4 * hh;
                float o0 = oacc[cb][rg*4+0] * invl, o1 = oacc[cb][rg*4+1] * invl;
                float o2 = oacc[cb][rg*4+2] * invl, o3 = oacc[cb][rg*4+3] * invl;
                float4 r;
                if (c0 >= 8) {
                    r.x = Lv[0] *o0 + Lv[1] *o1 + Lv[2] *o2 + Lv[3] *o3;
                    r.y = Lv[4] *o0 + Lv[5] *o1 + Lv[6] *o2 + Lv[7] *o3;
                    r.z = Lv[8] *o0 + Lv[9] *o1 + Lv[10]*o2 + Lv[11]*o3;
                    r.w = Lv[12]*o0 + Lv[13]*o1 + Lv[14]*o2 + Lv[15]*o3;
                } else {
                    r.x = o0; r.y = o1; r.z = o2; r.w = o3;
                }
                *(float4*)(ob + c0) = r;
            }
        }
    }
}

extern "C" void kernel_launch(void* const* d_in, const int* in_sizes, int n_in,
                              void* d_out, int out_size, void* d_ws, size_t ws_size,
                              hipStream_t stream) {
    const float* q = (const float*)d_in[0];
    const float* k = (const float*)d_in[1];
    const float* v = (const float*)d_in[2];
    const float* L = (const float*)d_in[3];
    float* o = (float*)d_out;
    f16* khs = (f16*)d_ws;                       // 16.78 MB
    f16* vhs = khs + (size_t)64 * 131072;        // 16.78 MB
    dim3 grid1(64, 16);
    ipa_pre<<<grid1, 256, 0, stream>>>(k, v, L, khs, vhs);
    ipa_attn<<<512, 256, 0, stream>>>(q, khs, vhs, L, o);
}